// Round 14
// baseline (99.001 us; speedup 1.0000x reference)
//
#include <hip/hip_runtime.h>
#include <math.h>
#include <stdint.h>

typedef unsigned long long u64;

#define EPS 1e-8f
#define FMAXV 3.402823466e38f

// ---------------- 2-D (y,x) cell parameters ----------------
#define GD2 64
#define NC2 (GD2 * GD2)          // 4096 cells
#define BLO (-6.0f)
#define INVCS (5.3333335f)       // 64/12; only monotone consistency needed
#define MARGIN 2e-4f             // >> max |frozen score - true dist^2| (~4e-5)

__device__ __forceinline__ int mcell(float v) {
    int c = (int)floorf((v - BLO) * INVCS);
    return min(max(c, 0), GD2 - 1);
}
// source key: row-major, x minor -> per-row x-ranges are contiguous spans
__device__ __forceinline__ int skey2(float x, float y) {
    return mcell(y) * GD2 + mcell(x);
}
// query key: serpentine x within y-rows (locality only; any order is correct)
__device__ __forceinline__ int qkey2(float x, float y) {
    int r = mcell(y), c = mcell(x);
    return r * GD2 + ((r & 1) ? (GD2 - 1 - c) : c);
}
__device__ __forceinline__ float finf() { return __uint_as_float(0x7f800000u); }

// Monotone float->uint key; (key_hi(d)<<32)|idx = lexicographic (d, idx)
// == jax.lax.top_k lowest-index tie-break (validated R8-R13).
__device__ __forceinline__ unsigned key_hi(float d) {
    unsigned b = __float_as_uint(d);
    return (b & 0x80000000u) ? ~b : (b | 0x80000000u);
}
__device__ __forceinline__ float key_d(u64 k) {
    unsigned h = (unsigned)(k >> 32);
    unsigned b = (h & 0x80000000u) ? (h & 0x7fffffffu) : ~h;
    return __uint_as_float(b);
}
__device__ __forceinline__ u64 shfl_xor_u64(u64 v, int m) {
    int lo = __shfl_xor((int)(unsigned)(v & 0xffffffffu), m, 64);
    int hi = __shfl_xor((int)(unsigned)(v >> 32), m, 64);
    return ((u64)(unsigned)hi << 32) | (unsigned)lo;
}
__device__ __forceinline__ u64 shfl_u64_from(u64 v, int l) {
    int lo = __shfl((int)(unsigned)(v & 0xffffffffu), l, 64);
    int hi = __shfl((int)(unsigned)(v >> 32), l, 64);
    return ((u64)(unsigned)hi << 32) | (unsigned)lo;
}
// Branchless sorted top-3 insert on u64 keys (strict '<' lexicographic).
__device__ __forceinline__ void insert3k(u64 k, u64& k0, u64& k1, u64& k2) {
    const bool c0 = k < k0, c1 = k < k1, c2 = k < k2;
    k2 = c1 ? k1 : (c2 ? k : k2);
    k1 = c0 ? k0 : (c1 ? k : k1);
    k0 = c0 ? k : k0;
}
// Wave-wide u64 min (all lanes receive the result).
__device__ __forceinline__ u64 wave_min_u64(u64 v) {
    #pragma unroll
    for (int r = 1; r < 64; r <<= 1) {
        u64 o = shfl_xor_u64(v, r);
        v = (o < v) ? o : v;
    }
    return v;
}

// ---------------- build: histogram / scan / scatter (validated R13) --------
__global__ void k_hist2D(const float* __restrict__ sp, int N,
                         const float* __restrict__ tp, int M,
                         int* __restrict__ scnt, int* __restrict__ qcnt) {
    int i = blockIdx.x * 256 + threadIdx.x;
    if (i < N) {
        atomicAdd(&scnt[skey2(sp[3 * i], sp[3 * i + 1])], 1);
    } else if (i < N + M) {
        int j = i - N;
        atomicAdd(&qcnt[qkey2(tp[3 * j], tp[3 * j + 1])], 1);
    }
}

__global__ __launch_bounds__(1024) void k_scan4k(int* __restrict__ scnt, int* __restrict__ qcnt,
                                                 int* __restrict__ soffs, int* __restrict__ qoffs) {
    int* cnt  = blockIdx.x ? qcnt : scnt;
    int* offs = blockIdx.x ? qoffs : soffs;
    __shared__ int sh[1024];
    const int t = threadIdx.x;
    int4 v = ((const int4*)cnt)[t];
    int s = v.x + v.y + v.z + v.w;
    sh[t] = s;
    __syncthreads();
    for (int o = 1; o < 1024; o <<= 1) {
        int u = (t >= o) ? sh[t - o] : 0;
        __syncthreads();
        sh[t] += u;
        __syncthreads();
    }
    int base = sh[t] - s;
    int4 e = make_int4(base, base + v.x, base + v.x + v.y, base + v.x + v.y + v.z);
    ((int4*)offs)[t] = e;
    ((int4*)cnt)[t]  = e;   // cursor
    if (t == 1023) offs[NC2] = base + s;
}

// FROZEN preproc folded into source scatter (validated R5/R8-R13):
// spts[pos] = (-2x,-2y,-2z, s2), s2 = (x*x + y*y) + z*z strict no-FMA.
__global__ void k_scat2D(const float* __restrict__ sp, int N,
                         const float* __restrict__ tp, int M,
                         int* __restrict__ scur, float4* __restrict__ spts, int* __restrict__ sidx,
                         int* __restrict__ qcur, float4* __restrict__ qpts) {
    int i = blockIdx.x * 256 + threadIdx.x;
    if (i < N) {
        float x = sp[3 * i], y = sp[3 * i + 1], z = sp[3 * i + 2];
        int pos = atomicAdd(&scur[skey2(x, y)], 1);
        float s2 = __fadd_rn(__fadd_rn(__fmul_rn(x, x), __fmul_rn(y, y)), __fmul_rn(z, z));
        spts[pos] = make_float4(-2.f * x, -2.f * y, -2.f * z, s2);
        sidx[pos] = i;
    } else if (i < N + M) {
        int j = i - N;
        float x = tp[3 * j], y = tp[3 * j + 1], z = tp[3 * j + 2];
        int pos = atomicAdd(&qcur[qkey2(x, y)], 1);
        qpts[pos] = make_float4(x, y, z, __int_as_float(j));
    }
}

// ---------------- wave-per-query 2-D windowed kNN + interpolation ----------
// One wave per sorted query, 2 queries/wave (unrolled -> cross-query ILP).
// Phase 0: 256 index-contiguous candidates centered on the query's cell,
// scanned WITH u64 (score,idx) keys; global top-3 T of that set via 3x
// wave-min extraction (keys unique -> exact) -> b3 = key_d(T2).
// Phase 1: window rows [cell(qy-w),cell(qy+w)] x cols [cell(qx-w),cell(qx+w)],
// w = sqrt(b3+MARGIN), scanning spans MINUS [p0,p1) (exact index subtraction
// -> no duplicate keys), per-lane state seeded from T. Final: ballot over
// changed lanes + snapshot-deduped insert3k merges (phase-1 keys are
// index-disjoint from the snapshot by construction).
// Coverage: any point outside (phase0 U window) has frozen score
// > b3 + MARGIN - 4e-5 > b3 >= final 3rd-best (mcell monotone) -> true top-3
// is scanned. Scoring = FROZEN formula (R5); selection = u64 keys (R8-R13).
#define SCORE_ONLY(pp) ({                                                     \
    float _a = fmaf((pp).z, qz, fmaf((pp).y, qy, __fmul_rn((pp).x, qx)));     \
    __fadd_rn(__fadd_rn(t2, _a), (pp).w); })

#define QPW 2   // queries per wave

__global__ __launch_bounds__(256) void k_knn_w3(
        const float4* __restrict__ spts, const int* __restrict__ sidx,
        const int* __restrict__ soffs, const float4* __restrict__ qpts,
        const float* __restrict__ feat, float* __restrict__ out,
        int N, int M, int C) {
    const int lane = threadIdx.x & 63;
    const int wave = __builtin_amdgcn_readfirstlane(threadIdx.x >> 6);
    const int qbase = (blockIdx.x * 4 + wave) * QPW;

    #pragma unroll
    for (int qi = 0; qi < QPW; ++qi) {
        const int qid = qbase + qi;                  // wave-uniform
        if (qid >= M) break;                         // uniform branch
        float4 qp = qpts[qid];
        const float qx = qp.x, qy = qp.y, qz = qp.z;
        const int orig = __float_as_int(qp.w);
        const float t2 = __fadd_rn(__fadd_rn(__fmul_rn(qx, qx), __fmul_rn(qy, qy)),
                                   __fmul_rn(qz, qz));   // FROZEN (R5)

        // ---- phase 0: 256 candidates centered on the query's (y,x) cell ----
        const int ck = mcell(qy) * GD2 + mcell(qx);
        const int ca = soffs[ck], cb = soffs[ck + 1];
        const int ctr = (ca + cb) >> 1;
        const int p0 = min(max(ctr - 128, 0), N - 256);
        const int p1 = p0 + 256;

        u64 k0 = ~0ULL, k1 = ~0ULL, k2 = ~0ULL;
        #pragma unroll
        for (int s = 0; s < 4; ++s) {
            const int p = p0 + lane + s * 64;
            float4 pt = spts[p];
            int j = sidx[p];
            float d = SCORE_ONLY(pt);
            insert3k(((u64)key_hi(d) << 32) | (unsigned)j, k0, k1, k2);
        }
        // global top-3 of the 256-set via 3x wave-min extraction (keys unique)
        u64 T0 = wave_min_u64(k0);
        { bool h = (k0 == T0); k0 = h ? k1 : k0; k1 = h ? k2 : k1; k2 = h ? ~0ULL : k2; }
        u64 T1 = wave_min_u64(k0);
        { bool h = (k0 == T1); k0 = h ? k1 : k0; k1 = h ? k2 : k1; }
        u64 T2 = wave_min_u64(k0);

        const float b3 = key_d(T2);
        const float w = sqrtf(__fadd_rn(b3, MARGIN));
        const int rlo = mcell(qy - w), rhi = mcell(qy + w);
        const int clo = mcell(qx - w), chi = mcell(qx + w);

        // ---- phase 1: window \ [p0,p1), seeded from T ----
        u64 a0 = T0, a1 = T1, a2 = T2;
        for (int r = rlo; r <= rhi; ++r) {
            const int b = r << 6;
            const int A = soffs[b + clo], B = soffs[b + chi + 1];
            const int Lend = min(B, p0);
            for (int p = A + lane; p < Lend; p += 64) {
                float4 pt = spts[p]; int j = sidx[p];
                float d = SCORE_ONLY(pt);
                insert3k(((u64)key_hi(d) << 32) | (unsigned)j, a0, a1, a2);
            }
            const int Rbeg = max(A, p1);
            for (int p = Rbeg + lane; p < B; p += 64) {
                float4 pt = spts[p]; int j = sidx[p];
                float d = SCORE_ONLY(pt);
                insert3k(((u64)key_hi(d) << 32) | (unsigned)j, a0, a1, a2);
            }
        }
        // ---- merge the few changed lanes (snapshot-deduped) ----
        const bool changed = (a0 != T0) || (a1 != T1) || (a2 != T2);
        u64 mb = __ballot(changed);
        const u64 S0 = T0, S1 = T1, S2 = T2;
        while (mb) {
            int l = __builtin_ctzll(mb);
            mb &= mb - 1;
            u64 m0 = shfl_u64_from(a0, l);
            u64 m1 = shfl_u64_from(a1, l);
            u64 m2 = shfl_u64_from(a2, l);
            if (m0 != S0 && m0 != S1 && m0 != S2) insert3k(m0, T0, T1, T2);
            if (m1 != S0 && m1 != S1 && m1 != S2) insert3k(m1, T0, T1, T2);
            if (m2 != S0 && m2 != S1 && m2 != S2) insert3k(m2, T0, T1, T2);
        }

        // FROZEN weights (R5): w = 1/(d+eps); w /= (w0+w1)+w2
        const float d0 = key_d(T0), d1 = key_d(T1), d2 = key_d(T2);
        const float w0r = __fdiv_rn(1.f, __fadd_rn(d0, EPS));
        const float w1r = __fdiv_rn(1.f, __fadd_rn(d1, EPS));
        const float w2r = __fdiv_rn(1.f, __fadd_rn(d2, EPS));
        const float sum = __fadd_rn(__fadd_rn(w0r, w1r), w2r);
        const float w0 = __fdiv_rn(w0r, sum);
        const float w1 = __fdiv_rn(w1r, sum);
        const float w2 = __fdiv_rn(w2r, sum);
        const int j0 = (int)(unsigned)(T0 & 0xffffffffu);
        const int j1 = (int)(unsigned)(T1 & 0xffffffffu);
        const int j2 = (int)(unsigned)(T2 & 0xffffffffu);

        // interpolation: whole wave on this query's row, float2/lane (C even)
        const float2* f0 = (const float2*)(feat + (size_t)j0 * C);
        const float2* f1 = (const float2*)(feat + (size_t)j1 * C);
        const float2* f2 = (const float2*)(feat + (size_t)j2 * C);
        float2* o = (float2*)(out + (size_t)orig * C);
        const int nc2 = C >> 1;
        for (int cc = lane; cc < nc2; cc += 64) {
            float2 a = f0[cc], b = f1[cc], d = f2[cc];
            o[cc] = make_float2(w0 * a.x + w1 * b.x + w2 * d.x,
                                w0 * a.y + w1 * b.y + w2 * d.y);
        }
    }
}

// ---------------- dense fallback (validated R7 path) ----------------
#define NW 16
__global__ void knn_preproc(const float* __restrict__ sp, float4* __restrict__ sp4, int N) {
    int j = blockIdx.x * blockDim.x + threadIdx.x;
    if (j < N) {
        float x = sp[3 * j + 0], y = sp[3 * j + 1], z = sp[3 * j + 2];
        float s2 = __fadd_rn(__fadd_rn(__fmul_rn(x, x), __fmul_rn(y, y)), __fmul_rn(z, z));
        sp4[j] = make_float4(-2.f * x, -2.f * y, -2.f * z, s2);
    }
}
__device__ __forceinline__ void insert3_bl(float d, int j,
                                           float& d0, float& d1, float& d2,
                                           int& i0, int& i1, int& i2) {
    const bool c0 = d < d0, c1 = d < d1, c2 = d < d2;
    const float nd2 = c1 ? d1 : (c2 ? d : d2);
    const int   ni2 = c1 ? i1 : (c2 ? j : i2);
    const float nd1 = c0 ? d0 : (c1 ? d : d1);
    const int   ni1 = c0 ? i0 : (c1 ? j : i1);
    const float nd0 = c0 ? d : d0;
    const int   ni0 = c0 ? j : i0;
    d0 = nd0; d1 = nd1; d2 = nd2;
    i0 = ni0; i1 = ni1; i2 = ni2;
}
#define SCORE_INSERT(p, jv) do {                                          \
    float _a = fmaf((p).z, tz, fmaf((p).y, ty, __fmul_rn((p).x, tx)));    \
    float _d = __fadd_rn(__fadd_rn(t2, _a), (p).w);                       \
    if (__any(_d < d2))                                                   \
        insert3_bl(_d, (jv), d0, d1, d2, i0, i1, i2);                     \
} while (0)
__global__ __launch_bounds__(1024, 8) void knn_dense(
    const float4* __restrict__ sp4, const float* __restrict__ feat,
    const float* __restrict__ tp, float* __restrict__ out,
    int N, int M, int C) {
    __shared__ float s_d[NW][3][64];
    __shared__ int   s_i[NW][3][64];
    __shared__ float s_w[3][64];
    __shared__ int   s_j[3][64];
    const int tid  = threadIdx.x;
    const int lane = tid & 63;
    const int wave = __builtin_amdgcn_readfirstlane(tid >> 6);
    const int mbase = blockIdx.x * 64;
    const int m = mbase + lane;
    float tx = 0.f, ty = 0.f, tz = 0.f;
    if (m < M) { tx = tp[3 * m + 0]; ty = tp[3 * m + 1]; tz = tp[3 * m + 2]; }
    const float t2 = __fadd_rn(__fadd_rn(__fmul_rn(tx, tx), __fmul_rn(ty, ty)),
                               __fmul_rn(tz, tz));
    float d0 = FMAXV, d1 = FMAXV, d2 = FMAXV;
    int   i0 = 0,     i1 = 0,     i2 = 0;
    const int chunk = (N + NW - 1) / NW;
    const int jbeg = wave * chunk;
    const int jend = min(jbeg + chunk, N);
    int j = jbeg;
    for (; j + 8 <= jend; j += 8) {
        float4 p0 = sp4[j + 0], p1 = sp4[j + 1], p2 = sp4[j + 2], p3 = sp4[j + 3];
        float4 p4 = sp4[j + 4], p5 = sp4[j + 5], p6 = sp4[j + 6], p7 = sp4[j + 7];
        SCORE_INSERT(p0, j + 0); SCORE_INSERT(p1, j + 1);
        SCORE_INSERT(p2, j + 2); SCORE_INSERT(p3, j + 3);
        SCORE_INSERT(p4, j + 4); SCORE_INSERT(p5, j + 5);
        SCORE_INSERT(p6, j + 6); SCORE_INSERT(p7, j + 7);
    }
    for (; j < jend; ++j) { float4 p = sp4[j]; SCORE_INSERT(p, j); }
    s_d[wave][0][lane] = d0; s_d[wave][1][lane] = d1; s_d[wave][2][lane] = d2;
    s_i[wave][0][lane] = i0; s_i[wave][1][lane] = i1; s_i[wave][2][lane] = i2;
    __syncthreads();
    if (wave == 0) {
        float b0 = FMAXV, b1 = FMAXV, b2 = FMAXV;
        int   j0 = 0,     j1 = 0,     j2 = 0;
        #pragma unroll
        for (int w = 0; w < NW; ++w)
            #pragma unroll
            for (int k = 0; k < 3; ++k)
                insert3_bl(s_d[w][k][lane], s_i[w][k][lane], b0, b1, b2, j0, j1, j2);
        float w0 = __fdiv_rn(1.f, __fadd_rn(b0, EPS));
        float w1 = __fdiv_rn(1.f, __fadd_rn(b1, EPS));
        float w2 = __fdiv_rn(1.f, __fadd_rn(b2, EPS));
        float sum = __fadd_rn(__fadd_rn(w0, w1), w2);
        s_w[0][lane] = __fdiv_rn(w0, sum);
        s_w[1][lane] = __fdiv_rn(w1, sum);
        s_w[2][lane] = __fdiv_rn(w2, sum);
        s_j[0][lane] = j0; s_j[1][lane] = j1; s_j[2][lane] = j2;
    }
    __syncthreads();
    const int tm = tid >> 4;
    const int qq = tid & 15;
    const int gm = mbase + tm;
    if (gm < M) {
        const int nv = C >> 6;
        const float w0 = s_w[0][tm], w1 = s_w[1][tm], w2 = s_w[2][tm];
        const float4* f0 = (const float4*)(feat + (size_t)s_j[0][tm] * C) + qq * nv;
        const float4* f1 = (const float4*)(feat + (size_t)s_j[1][tm] * C) + qq * nv;
        const float4* f2 = (const float4*)(feat + (size_t)s_j[2][tm] * C) + qq * nv;
        float4* o = (float4*)(out + (size_t)gm * C) + qq * nv;
        for (int r = 0; r < nv; ++r) {
            float4 a = f0[r], b = f1[r], c = f2[r];
            float4 v;
            v.x = w0 * a.x + w1 * b.x + w2 * c.x;
            v.y = w0 * a.y + w1 * b.y + w2 * c.y;
            v.z = w0 * a.z + w1 * b.z + w2 * c.z;
            v.w = w0 * a.w + w1 * b.w + w2 * c.w;
            o[r] = v;
        }
    }
}

// ---------------- host ----------------
static inline size_t align256(size_t x) { return (x + 255) & ~(size_t)255; }

extern "C" void kernel_launch(void* const* d_in, const int* in_sizes, int n_in,
                              void* d_out, int out_size, void* d_ws, size_t ws_size,
                              hipStream_t stream) {
    const float* sp   = (const float*)d_in[0];  // source_points [N,3]
    const float* feat = (const float*)d_in[1];  // source_features [N,C]
    const float* tp   = (const float*)d_in[2];  // target_points [M,3]
    float* out = (float*)d_out;                 // [M,C] fp32

    const int N = in_sizes[0] / 3;
    const int C = in_sizes[1] / N;
    const int M = in_sizes[2] / 3;

    // ws layout (2-D windowed wave-per-query path)
    size_t oScnt  = 0;                                        // NC2 ints
    size_t oQcnt  = oScnt + (size_t)NC2 * 4;                  // NC2 ints (adjacent -> one memset)
    size_t oSoffs = align256(oQcnt + (size_t)NC2 * 4);        // NC2+1 ints
    size_t oQoffs = align256(oSoffs + (size_t)(NC2 + 1) * 4); // NC2+1 ints
    size_t oSpts  = align256(oQoffs + (size_t)(NC2 + 1) * 4); // N float4
    size_t oSidx  = align256(oSpts + (size_t)N * 16);         // N ints
    size_t oQpts  = align256(oSidx + (size_t)N * 4);          // M float4
    size_t need   = oQpts + (size_t)M * 16;

    if (ws_size >= need && (C & 1) == 0 && N >= 256) {
        char* ws = (char*)d_ws;
        int*    scnt  = (int*)(ws + oScnt);
        int*    qcnt  = (int*)(ws + oQcnt);
        int*    soffs = (int*)(ws + oSoffs);
        int*    qoffs = (int*)(ws + oQoffs);
        float4* spts  = (float4*)(ws + oSpts);
        int*    sidxp = (int*)(ws + oSidx);
        float4* qpts  = (float4*)(ws + oQpts);

        hipMemsetAsync(scnt, 0, (size_t)2 * NC2 * 4, stream);
        int nmBlocks = (N + M + 255) / 256;
        k_hist2D<<<nmBlocks, 256, 0, stream>>>(sp, N, tp, M, scnt, qcnt);
        k_scan4k<<<2, 1024, 0, stream>>>(scnt, qcnt, soffs, qoffs);
        k_scat2D<<<nmBlocks, 256, 0, stream>>>(sp, N, tp, M, scnt, spts, sidxp, qcnt, qpts);
        int qblocks = (M + 4 * QPW - 1) / (4 * QPW);
        k_knn_w3<<<qblocks, 256, 0, stream>>>(spts, sidxp, soffs, qpts, feat, out, N, M, C);
    } else {
        // dense fallback (validated R7)
        float4* sp4 = (float4*)d_ws;
        knn_preproc<<<(N + 255) / 256, 256, 0, stream>>>(sp, sp4, N);
        knn_dense<<<(M + 63) / 64, 1024, 0, stream>>>(sp4, feat, tp, out, N, M, C);
    }
}